// Round 12
// baseline (105.323 us; speedup 1.0000x reference)
//
#include <hip/hip_runtime.h>
#include <math.h>

// DAS beamforming: out[b][c][p] = sum_s data[b][c][s][t(s,p)]
// Table chain: ONLY the f64-emulated chain is proven bit-exact. DO NOT change.
// Cost model (fits r5-r11): TD-serialized VMEM wave-instrs, ~(10+1.4*lines)
// cyc each; need >=16 waves/CU to hide latency (r11: 8/CU regressed).
// r12: per (block=16x16px, sensor) the t-window spans <=56 slots (|grad dis|=1,
// monotone f32 chain) -> stage 64 slots (1KB) into LDS with ONE coalesced
// dwordx4 wave-instr; consumers ds_read_b128 win[t-tmin] (LDS pipe, off TD).
// tmin = delay_entry(nearest corner) in-registers (bit-exact, same function).
// Batches of 8 sensors = 8KB LDS; 1px/thread keeps 4096 waves (16/CU).

#define NXY 512
#define S_CNT 128
#define T_CNT 2048
#define CH 8                       // B*2 = 4*2
#define CH_STRIDE (S_CNT * T_CNT)  // 262144 floats between channels (orig layout)
#define NPIX (NXY * NXY)
#define TAB_BYTES (NPIX * 2)       // 512 KB u16 table

#pragma float_control(push)
#pragma float_control(precise, on)
__device__ __forceinline__ unsigned short delay_entry(int adx, int ady) {
    const double DX32 = (double)1e-4f;                        // f32 const, exact widen
    const double R1 = (double)(float)(1.0 / 1550.0);          // CR f32 reciprocal
    const double R2 = (double)(float)(1.0 / (double)2.5e-8f); // = 4.0e7 exactly
    float dxf = (float)((double)adx * DX32);        // exact f64 product -> f32 round
    float dyf = (float)((double)ady * DX32);
    float a2 = (float)((double)dxf * (double)dxf);  // exact in f64 -> f32 round
    float b2 = (float)((double)dyf * (double)dyf);
    float sum = (float)((double)a2 + (double)b2);   // exact in f64 -> f32 round
    float dis = (float)sqrt((double)sum);           // CR f32 sqrt via Figueroa
    float q1 = (float)((double)dis * R1);           // CR f32 mul (exact f64 product)
    float q2 = (float)((double)q1 * R2);            // CR f32 mul (exact f64 product)
    return (unsigned short)(int)q2;                 // trunc = convert<s32>; max 1864
}

__device__ __forceinline__ unsigned int bf16_rne(float f) {
    unsigned int x = __float_as_uint(f);
    return (x + 0x7fffu + ((x >> 16) & 1u)) >> 16;  // round-to-nearest-even
}

// Fused prep, 4 slots/thread: table entries (ushort4 store) + transpose-convert
// (8ch,128s,2048t)f32 -> (128s,2048t) x (8ch bf16 in 16B).
__global__ __launch_bounds__(256) void prep(const float* __restrict__ data,
                                            unsigned short* __restrict__ tab,
                                            uint4* __restrict__ d2b) {
    int i0 = (blockIdx.x * 256 + threadIdx.x) * 4;  // 0..262140, 4-aligned
    int adx = i0 >> 9;
    int ady0 = i0 & 511;
    ushort4 te;
    te.x = delay_entry(adx, ady0);
    te.y = delay_entry(adx, ady0 + 1);
    te.z = delay_entry(adx, ady0 + 2);
    te.w = delay_entry(adx, ady0 + 3);
    *(ushort4*)(tab + i0) = te;

    float4 v[CH];
#pragma unroll
    for (int k = 0; k < CH; ++k) v[k] = *(const float4*)(data + k * CH_STRIDE + i0);
#pragma unroll
    for (int j = 0; j < 4; ++j) {
        const float* c = (const float*)v;  // v[k] components: c[4k+j]
        unsigned int w0 = bf16_rne(c[0 * 4 + j]) | (bf16_rne(c[1 * 4 + j]) << 16);
        unsigned int w1 = bf16_rne(c[2 * 4 + j]) | (bf16_rne(c[3 * 4 + j]) << 16);
        unsigned int w2 = bf16_rne(c[4 * 4 + j]) | (bf16_rne(c[5 * 4 + j]) << 16);
        unsigned int w3 = bf16_rne(c[6 * 4 + j]) | (bf16_rne(c[7 * 4 + j]) << 16);
        d2b[i0 + j] = make_uint4(w0, w1, w2, w3);
    }
}
#pragma float_control(pop)

__device__ __forceinline__ float bflo(unsigned int u) { return __uint_as_float(u << 16); }
__device__ __forceinline__ float bfhi(unsigned int u) { return __uint_as_float(u & 0xffff0000u); }

// Staged gather: block = 16x16 px (4 waves, 8x8 wave tiles), 1 px/thread.
// Batches of 8 sensors: each wave stages 2 windows (64 slots x 16B = one
// coalesced dwordx4 instr), then all threads read win[j][t - tmin[j]] via LDS.
__global__ __launch_bounds__(256) void das_stage(const uint4* __restrict__ d2b,
                                                 const unsigned short* __restrict__ tab,
                                                 const int* __restrict__ sxy,
                                                 float* __restrict__ out) {
    __shared__ int sx[S_CNT];
    __shared__ int sy[S_CNT];
    __shared__ int tmins[8];
    __shared__ uint4 win[8][64];  // 8 KB
    int tid = threadIdx.x;
    if (tid < S_CNT) {
        sx[tid] = sxy[2 * tid];
        sy[tid] = sxy[2 * tid + 1];
    }
    __syncthreads();

    int bx = blockIdx.x & 31;
    int by = blockIdx.x >> 5;
    int ix0 = bx << 4, iy0 = by << 4;
    // lane bits: iy[2:0]=tid[2:0], ix[2:0]=tid[5:3]; wave bits: iy[3]=tid[6], ix[3]=tid[7]
    int iy = iy0 | (((tid >> 6) & 1) << 3) | (tid & 7);
    int ix = ix0 | ((tid >> 7) << 3) | ((tid >> 3) & 7);
    int wv = tid >> 6;    // wave id 0..3
    int lane = tid & 63;

    float acc[CH];
#pragma unroll
    for (int k = 0; k < CH; ++k) acc[k] = 0.0f;

    for (int b = 0; b < S_CNT / 8; ++b) {
        __syncthreads();  // previous batch fully consumed before overwrite
#pragma unroll
        for (int jj = 0; jj < 2; ++jj) {
            int j = (wv << 1) | jj;
            int s = (b << 3) | j;
            int sxv = sx[s], syv = sy[s];
            // nearest-corner |dx|,|dy| over the 16x16 tile (wave-uniform)
            int axmin = sxv < ix0 ? ix0 - sxv : (sxv > ix0 + 15 ? sxv - (ix0 + 15) : 0);
            int aymin = syv < iy0 ? iy0 - syv : (syv > iy0 + 15 ? syv - (iy0 + 15) : 0);
            int tmin = (int)delay_entry(axmin, aymin);  // == tab[axmin][aymin], bit-exact
            win[j][lane] = d2b[(s << 11) + tmin + lane];  // window <=56 slots, 64 staged
            if (lane == 0) tmins[j] = tmin;
        }
        __syncthreads();
#pragma unroll
        for (int j = 0; j < 8; ++j) {
            int s = (b << 3) | j;
            int dxi = sx[s] - ix;
            int dyi = sy[s] - iy;
            int adx = dxi < 0 ? -dxi : dxi;
            int ady = dyi < 0 ? -dyi : dyi;
            int t = (int)tab[(adx << 9) | ady];
            uint4 w = win[j][t - tmins[j]];
            acc[0] += bflo(w.x);  // per-channel s-ascending: deterministic
            acc[1] += bfhi(w.x);
            acc[2] += bflo(w.y);
            acc[3] += bfhi(w.y);
            acc[4] += bflo(w.z);
            acc[5] += bfhi(w.z);
            acc[6] += bflo(w.w);
            acc[7] += bfhi(w.w);
        }
    }

    int pix = (ix << 9) | iy;
#pragma unroll
    for (int k = 0; k < CH; ++k) out[k * NPIX + pix] = acc[k];
}

// ---------- fallback path (ws too small): r5-proven build_table + das_main ----------
#pragma float_control(push)
#pragma float_control(precise, on)
__global__ __launch_bounds__(256) void build_table(unsigned short* __restrict__ tab) {
    int idx = blockIdx.x * 256 + threadIdx.x;
    tab[idx] = delay_entry(idx >> 9, idx & 511);
}
#pragma float_control(pop)

__global__ __launch_bounds__(256) void das_main(const float* __restrict__ data,
                                                const unsigned short* __restrict__ tab,
                                                const int* __restrict__ sxy,
                                                float* __restrict__ out) {
    __shared__ int sx[S_CNT];
    __shared__ int sy[S_CNT];
    int tid = threadIdx.x;
    if (tid < S_CNT) {
        sx[tid] = sxy[2 * tid];
        sy[tid] = sxy[2 * tid + 1];
    }
    __syncthreads();
    int iy = ((blockIdx.x & 31) << 4) | (tid & 15);
    int ix = ((blockIdx.x >> 5) << 4) | (tid >> 4);
    float acc[CH];
#pragma unroll
    for (int k = 0; k < CH; ++k) acc[k] = 0.0f;
#pragma unroll 4
    for (int s = 0; s < S_CNT; ++s) {
        int dxi = sx[s] - ix;
        int dyi = sy[s] - iy;
        int adx = dxi < 0 ? -dxi : dxi;
        int ady = dyi < 0 ? -dyi : dyi;
        int t = (int)tab[(adx << 9) | ady];
        const float* p = data + (s << 11) + t;
#pragma unroll
        for (int k = 0; k < CH; ++k) acc[k] += p[(size_t)k * CH_STRIDE];
    }
    int pix = (ix << 9) | iy;
#pragma unroll
    for (int k = 0; k < CH; ++k) out[k * NPIX + pix] = acc[k];
}

extern "C" void kernel_launch(void* const* d_in, const int* in_sizes, int n_in,
                              void* d_out, int out_size, void* d_ws, size_t ws_size,
                              hipStream_t stream) {
    const float* data = (const float*)d_in[0];     // (4,2,128,2048) f32
    const int* sxy = (const int*)d_in[1];          // (128,2) i32
    float* out = (float*)d_out;                    // (4,2,512,512) f32
    unsigned short* tab = (unsigned short*)d_ws;   // 512 KB

    size_t need = (size_t)TAB_BYTES + (size_t)CH_STRIDE * 16;  // 512KB + 4MB
    if (ws_size >= need) {
        uint4* d2b = (uint4*)((char*)d_ws + TAB_BYTES);
        prep<<<NPIX / 1024, 256, 0, stream>>>(data, tab, d2b);
        das_stage<<<1024, 256, 0, stream>>>(d2b, tab, sxy, out);
    } else {
        build_table<<<NPIX / 256, 256, 0, stream>>>(tab);
        das_main<<<1024, 256, 0, stream>>>(data, tab, sxy, out);
    }
}

// Round 13
// 97.137 us; speedup vs baseline: 1.0843x; 1.0843x over previous
//
#include <hip/hip_runtime.h>
#include <math.h>

// DAS beamforming: out[b][c][p] = sum_s data[b][c][s][t(s,p)]
// Table chain: ONLY the f64-emulated chain is proven bit-exact. DO NOT change.
// Ledger: r10 lean gather (2 VMEM/iter, 16 waves/CU) = 38us, TD-bound
// (model: ~(10+1.4*lines) cyc per VMEM wave-instr, serialized at TD/L1).
// r11 (2px/thread, dwordx2 tab) cut VMEM 25% but halved waves to 8/CU -> 45us.
// r12 LDS staging: TD gain eaten by VALU/barriers/LDS machinery -> 49.7us.
// r13 = r11 + r9's s-split: 512-thr blocks, 2 teams x 64 sensors, 2px/thread
// -> 3 VMEM per 2px per sensor AND 4096 waves (16/CU). Team partials combined
// through LDS in fixed order (deterministic; r9-verified).

#define NXY 512
#define S_CNT 128
#define T_CNT 2048
#define CH 8                       // B*2 = 4*2
#define CH_STRIDE (S_CNT * T_CNT)  // 262144 floats between channels (orig layout)
#define NPIX (NXY * NXY)
#define TAB_BYTES (NPIX * 2)       // 512 KB u16 table

#pragma float_control(push)
#pragma float_control(precise, on)
__device__ __forceinline__ unsigned short delay_entry(int adx, int ady) {
    const double DX32 = (double)1e-4f;                        // f32 const, exact widen
    const double R1 = (double)(float)(1.0 / 1550.0);          // CR f32 reciprocal
    const double R2 = (double)(float)(1.0 / (double)2.5e-8f); // = 4.0e7 exactly
    float dxf = (float)((double)adx * DX32);        // exact f64 product -> f32 round
    float dyf = (float)((double)ady * DX32);
    float a2 = (float)((double)dxf * (double)dxf);  // exact in f64 -> f32 round
    float b2 = (float)((double)dyf * (double)dyf);
    float sum = (float)((double)a2 + (double)b2);   // exact in f64 -> f32 round
    float dis = (float)sqrt((double)sum);           // CR f32 sqrt via Figueroa
    float q1 = (float)((double)dis * R1);           // CR f32 mul (exact f64 product)
    float q2 = (float)((double)q1 * R2);            // CR f32 mul (exact f64 product)
    return (unsigned short)(int)q2;                 // trunc = convert<s32>; max 1864
}

__device__ __forceinline__ unsigned int bf16_rne(float f) {
    unsigned int x = __float_as_uint(f);
    return (x + 0x7fffu + ((x >> 16) & 1u)) >> 16;  // round-to-nearest-even
}

// Fused prep, 4 slots/thread: table entries (ushort4 store) + transpose-convert
// (8ch,128s,2048t)f32 -> (128s,2048t) x (8ch bf16 in 16B).
__global__ __launch_bounds__(256) void prep(const float* __restrict__ data,
                                            unsigned short* __restrict__ tab,
                                            uint4* __restrict__ d2b) {
    int i0 = (blockIdx.x * 256 + threadIdx.x) * 4;  // 0..262140, 4-aligned
    int adx = i0 >> 9;
    int ady0 = i0 & 511;
    ushort4 te;
    te.x = delay_entry(adx, ady0);
    te.y = delay_entry(adx, ady0 + 1);
    te.z = delay_entry(adx, ady0 + 2);
    te.w = delay_entry(adx, ady0 + 3);
    *(ushort4*)(tab + i0) = te;

    float4 v[CH];
#pragma unroll
    for (int k = 0; k < CH; ++k) v[k] = *(const float4*)(data + k * CH_STRIDE + i0);
#pragma unroll
    for (int j = 0; j < 4; ++j) {
        const float* c = (const float*)v;  // v[k] components: c[4k+j]
        unsigned int w0 = bf16_rne(c[0 * 4 + j]) | (bf16_rne(c[1 * 4 + j]) << 16);
        unsigned int w1 = bf16_rne(c[2 * 4 + j]) | (bf16_rne(c[3 * 4 + j]) << 16);
        unsigned int w2 = bf16_rne(c[4 * 4 + j]) | (bf16_rne(c[5 * 4 + j]) << 16);
        unsigned int w3 = bf16_rne(c[6 * 4 + j]) | (bf16_rne(c[7 * 4 + j]) << 16);
        d2b[i0 + j] = make_uint4(w0, w1, w2, w3);
    }
}
#pragma float_control(pop)

__device__ __forceinline__ float bflo(unsigned int u) { return __uint_as_float(u << 16); }
__device__ __forceinline__ float bfhi(unsigned int u) { return __uint_as_float(u & 0xffff0000u); }

// Gather: 512 threads = 2 teams x 256; team t does sensors [64t, 64t+64).
// Thread = 2 iy-adjacent px x 8 ch. Wave = 8ix x 8 iy-pairs (8x16 px).
// Block pixel tile: 16 ix x 32 iy. Tab: one aligned-down dwordx2 covers the
// consecutive entry pair {m, m+1} = {ady(iy0), ady(iy0+1)} (verified r11).
__global__ __launch_bounds__(512) void das_split2(const uint4* __restrict__ d2b,
                                                  const unsigned short* __restrict__ tab,
                                                  const int* __restrict__ sxy,
                                                  float* __restrict__ out) {
    __shared__ int sx[S_CNT];
    __shared__ int sy[S_CNT];
    __shared__ float part[256 * 16];  // 16 KB: team1 partials (16 floats/slot)
    int tid = threadIdx.x;
    if (tid < S_CNT) {
        sx[tid] = sxy[2 * tid];
        sy[tid] = sxy[2 * tid + 1];
    }
    __syncthreads();

    int lid = tid & 255;
    int team = tid >> 8;
    // grid: 32 bx (16-ix tiles) x 16 by (32-iy tiles) = 512 blocks
    int bx = blockIdx.x & 31;
    int by = blockIdx.x >> 5;
    int ix = (bx << 4) | ((lid >> 7) << 3) | ((lid >> 3) & 7);
    int iy0 = (by << 5) | (((lid >> 6) & 1) << 4) | ((lid & 7) << 1);  // even

    float acc0[CH], acc1[CH];
#pragma unroll
    for (int k = 0; k < CH; ++k) { acc0[k] = 0.0f; acc1[k] = 0.0f; }

    const char* tabb = (const char*)tab;
    int sbase = team << 6;

#pragma unroll 4
    for (int i = 0; i < 64; ++i) {
        int s = sbase + i;
        int dxi = sx[s] - ix;
        int adx = dxi < 0 ? -dxi : dxi;
        int dy0 = sy[s] - iy0;
        int ady0 = dy0 < 0 ? -dy0 : dy0;
        int dy1 = dy0 - 1;
        int ady1 = dy1 < 0 ? -dy1 : dy1;
        int m = ady0 < ady1 ? ady0 : ady1;          // {m, m+1} = {ady0, ady1}
        int boff = (((adx << 9) + m) << 1) & ~3;    // aligned-down dword offset
        uint2 d = *(const uint2*)(tabb + boff);
        unsigned sel = (unsigned)(m & 1);
        unsigned em = sel ? (d.x >> 16) : (d.x & 0xffffu);   // entry[m]
        unsigned em1 = sel ? (d.y & 0xffffu) : (d.x >> 16);  // entry[m+1]
        unsigned t0 = (ady0 == m) ? em : em1;       // t for pixel iy0
        unsigned t1 = (ady0 == m) ? em1 : em;       // t for pixel iy0+1
        uint4 w0 = d2b[(s << 11) + t0];
        uint4 w1 = d2b[(s << 11) + t1];
        acc0[0] += bflo(w0.x);  // per-channel s-ascending within team
        acc0[1] += bfhi(w0.x);
        acc0[2] += bflo(w0.y);
        acc0[3] += bfhi(w0.y);
        acc0[4] += bflo(w0.z);
        acc0[5] += bfhi(w0.z);
        acc0[6] += bflo(w0.w);
        acc0[7] += bfhi(w0.w);
        acc1[0] += bflo(w1.x);
        acc1[1] += bfhi(w1.x);
        acc1[2] += bflo(w1.y);
        acc1[3] += bfhi(w1.y);
        acc1[4] += bflo(w1.z);
        acc1[5] += bfhi(w1.z);
        acc1[6] += bflo(w1.w);
        acc1[7] += bfhi(w1.w);
    }

    if (team) {
        float4* pp = (float4*)(part + lid * 16);
        pp[0] = make_float4(acc0[0], acc0[1], acc0[2], acc0[3]);
        pp[1] = make_float4(acc0[4], acc0[5], acc0[6], acc0[7]);
        pp[2] = make_float4(acc1[0], acc1[1], acc1[2], acc1[3]);
        pp[3] = make_float4(acc1[4], acc1[5], acc1[6], acc1[7]);
    }
    __syncthreads();
    if (!team) {
        const float* pp = part + lid * 16;
        int pix = (ix << 9) | iy0;  // iy0, iy0+1 adjacent -> float2 store
#pragma unroll
        for (int k = 0; k < CH; ++k) {
            // final = team0_partial + team1_partial (fixed order, deterministic)
            *(float2*)(out + k * NPIX + pix) =
                make_float2(acc0[k] + pp[k], acc1[k] + pp[8 + k]);
        }
    }
}

// ---------- fallback path (ws too small): r5-proven build_table + das_main ----------
#pragma float_control(push)
#pragma float_control(precise, on)
__global__ __launch_bounds__(256) void build_table(unsigned short* __restrict__ tab) {
    int idx = blockIdx.x * 256 + threadIdx.x;
    tab[idx] = delay_entry(idx >> 9, idx & 511);
}
#pragma float_control(pop)

__global__ __launch_bounds__(256) void das_main(const float* __restrict__ data,
                                                const unsigned short* __restrict__ tab,
                                                const int* __restrict__ sxy,
                                                float* __restrict__ out) {
    __shared__ int sx[S_CNT];
    __shared__ int sy[S_CNT];
    int tid = threadIdx.x;
    if (tid < S_CNT) {
        sx[tid] = sxy[2 * tid];
        sy[tid] = sxy[2 * tid + 1];
    }
    __syncthreads();
    int iy = ((blockIdx.x & 31) << 4) | (tid & 15);
    int ix = ((blockIdx.x >> 5) << 4) | (tid >> 4);
    float acc[CH];
#pragma unroll
    for (int k = 0; k < CH; ++k) acc[k] = 0.0f;
#pragma unroll 4
    for (int s = 0; s < S_CNT; ++s) {
        int dxi = sx[s] - ix;
        int dyi = sy[s] - iy;
        int adx = dxi < 0 ? -dxi : dxi;
        int ady = dyi < 0 ? -dyi : dyi;
        int t = (int)tab[(adx << 9) | ady];
        const float* p = data + (s << 11) + t;
#pragma unroll
        for (int k = 0; k < CH; ++k) acc[k] += p[(size_t)k * CH_STRIDE];
    }
    int pix = (ix << 9) | iy;
#pragma unroll
    for (int k = 0; k < CH; ++k) out[k * NPIX + pix] = acc[k];
}

extern "C" void kernel_launch(void* const* d_in, const int* in_sizes, int n_in,
                              void* d_out, int out_size, void* d_ws, size_t ws_size,
                              hipStream_t stream) {
    const float* data = (const float*)d_in[0];     // (4,2,128,2048) f32
    const int* sxy = (const int*)d_in[1];          // (128,2) i32
    float* out = (float*)d_out;                    // (4,2,512,512) f32
    unsigned short* tab = (unsigned short*)d_ws;   // 512 KB

    size_t need = (size_t)TAB_BYTES + (size_t)CH_STRIDE * 16;  // 512KB + 4MB
    if (ws_size >= need) {
        uint4* d2b = (uint4*)((char*)d_ws + TAB_BYTES);
        prep<<<NPIX / 1024, 256, 0, stream>>>(data, tab, d2b);
        das_split2<<<512, 512, 0, stream>>>(d2b, tab, sxy, out);
    } else {
        build_table<<<NPIX / 256, 256, 0, stream>>>(tab);
        das_main<<<1024, 256, 0, stream>>>(data, tab, sxy, out);
    }
}